// Round 9
// baseline (326.478 us; speedup 1.0000x reference)
//
#include <hip/hip_runtime.h>
#include <hip/hip_bf16.h>
#include <cstdint>
#include <cstddef>

#define AS1 __attribute__((address_space(1)))
#define AS3 __attribute__((address_space(3)))

typedef __bf16 bf16x8 __attribute__((ext_vector_type(8)));
typedef float  floatx4 __attribute__((ext_vector_type(4)));

__device__ __forceinline__ void load_lds16(const void* g, void* l) {
    __builtin_amdgcn_global_load_lds((AS1 void*)g, (AS3 void*)l, 16, 0, 0);
}

__device__ __forceinline__ float fexp2(float x) { return __builtin_amdgcn_exp2f(x); }
__device__ __forceinline__ float flog2(float x) { return __builtin_amdgcn_logf(x); }

// EXACT degree sort of the 2048 hidden features, deg(f) = f % 127.
// deg d<16 has 17 features (16 main + 1 leftover f=2032+d); deg 16..126 has 16.
// sorted p < 272 (=17*16): d = p/17, r = p%17: f = r<16 ? d + r*127 : 2032+d
// sorted p >= 272:         d = 16 + (p-272)/16, j = (p-272)%16: f = d + j*127
__device__ __forceinline__ int resp_s(int p) {
    return p < 272 ? p / 17 : 16 + ((p - 272) >> 4);
}
__device__ __forceinline__ int invp_s(int p) {
    if (p < 272) { int d = p / 17; int r = p - d * 17;
                   return r < 16 ? d + r * 127 : 2032 + d; }
    int d = 16 + ((p - 272) >> 4); int j = (p - 272) & 15;
    return d + j * 127;
}
// number of features with degree <= D
__device__ __forceinline__ int cnt_le(int D) {
    return D < 16 ? (D + 1) * 17 : 272 + ((D - 15) << 4);
}

// ---------------------------------------------------------------------------
// Prep: masks + fp32->bf16 + exact degree-sort, coalesced both sides via LDS.
// ---------------------------------------------------------------------------
__global__ __launch_bounds__(256)
void prep_all(const float* __restrict__ x,  const float* __restrict__ W0,
              const float* __restrict__ W1, const float* __restrict__ W2,
              const float* __restrict__ W3,
              __bf16* __restrict__ xb,  __bf16* __restrict__ w0m,
              __bf16* __restrict__ w1m, __bf16* __restrict__ w2m,
              __bf16* __restrict__ w3m)
{
    __shared__ float lds[2048];
    const int blk = blockIdx.x;
    const int tid = threadIdx.x;
    const int t8  = tid * 8;

    if (blk < 640) {                       // direct regions (x, W0)
        bf16x8 o;
        if (blk < 512) {                   // x copy
            size_t base = (size_t)blk * 2048 + t8;
            floatx4 a = *(const floatx4*)(x + base);
            floatx4 b = *(const floatx4*)(x + base + 4);
#pragma unroll
            for (int j = 0; j < 4; ++j) { o[j] = (__bf16)a[j]; o[4 + j] = (__bf16)b[j]; }
            *(bf16x8*)(xb + base) = o;
        } else {                           // W0: dst[p_n][c] = W0[invp(p_n)][c] * mask
            long idx = (long)(blk - 512) * 2048 + t8;
            int p_n = (int)(idx >> 7);
            int c   = (int)(idx & 127);
            int dg  = resp_s(p_n);
            const float* s = W0 + (long)invp_s(p_n) * 128 + c;
            floatx4 a = *(const floatx4*)s;
            floatx4 b = *(const floatx4*)(s + 4);
#pragma unroll
            for (int j = 0; j < 8; ++j) {
                float v = j < 4 ? a[j] : b[j - 4];
                o[j] = (__bf16)((dg >= c + j) ? v : 0.0f);
            }
            *(bf16x8*)(w0m + idx) = o;
        }
        return;
    }

    // permuted-column regions: one dst row per block
    const float* srow; __bf16* drow; int deg_n; bool strict;
    if (blk < 2688) {
        int p_n = blk - 640;
        srow = W1 + (size_t)invp_s(p_n) * 2048; drow = w1m + (size_t)p_n * 2048;
        deg_n = resp_s(p_n); strict = false;
    } else if (blk < 4736) {
        int p_n = blk - 2688;
        srow = W2 + (size_t)invp_s(p_n) * 2048; drow = w2m + (size_t)p_n * 2048;
        deg_n = resp_s(p_n); strict = false;
    } else {
        int n = blk - 4736;
        srow = W3 + (size_t)n * 2048; drow = w3m + (size_t)n * 2048;
        deg_n = n >> 5; strict = true;
    }
    floatx4 a = *(const floatx4*)(srow + t8);
    floatx4 b = *(const floatx4*)(srow + t8 + 4);
    *(floatx4*)&lds[t8]     = a;
    *(floatx4*)&lds[t8 + 4] = b;
    __syncthreads();
    bf16x8 o;
#pragma unroll
    for (int j = 0; j < 8; ++j) {
        int p = t8 + j;
        float v = lds[invp_s(p)];
        int dg = resp_s(p);
        bool keep = strict ? (deg_n > dg) : (deg_n >= dg);
        o[j] = (__bf16)(keep ? v : 0.0f);
    }
    *(bf16x8*)(drow + t8) = o;
}

// ---------------------------------------------------------------------------
// bf16 MFMA GEMM, BK=64, C[M,N] = A[M,K] * Bw[N,K]^T + bias, optional ReLU.
// Exact K-prefix skip (no tail chunk):
//   LMODE 0: sorted N, sorted K (g1/g2): prefix = cnt_le(resp(128bn+127))
//   LMODE 1: natural N, sorted K (g3):   prefix = cnt_le(min(4bn+2,126))
//   LMODE 2: sorted N, natural K (g0):   prefix = resp(128bn+127)+1
// LPT: bn reversed so longest tiles dispatch first.
// TLAYOUT: store bf16 batch-interleaved th2[b>>6][col][b&63].
// PERMBIAS: bias indexed through invp_s(col).
// ---------------------------------------------------------------------------
template <bool RELU, bool OBF16, bool TLAYOUT, bool PERMBIAS, int LMODE>
__global__ __launch_bounds__(256, 4)
void gemm_bt(const __bf16* __restrict__ A, const __bf16* __restrict__ Bw,
             const float* __restrict__ bias, void* __restrict__ Cout,
             int N, int K)
{
    __shared__ __align__(16) __bf16 lsA[128 * 64];   // 16 KB
    __shared__ __align__(16) __bf16 lsB[128 * 64];   // 16 KB
    const int tid  = threadIdx.x;
    const int wave = tid >> 6;
    const int lane = tid & 63;
    const int bm = blockIdx.x;
    const int bn = (gridDim.y - 1) - blockIdx.y;     // LPT order
    const int wm = wave >> 1, wn = wave & 1;

    // staging: 32 chunks of 1KB (A:0..15, B:16..31), 8 per wave.
    // chunk j covers rows [8j,8j+8); DMA puts lane l at LDS slot (l&7), so we
    // read global col-block (l&7)^(l>>3) -> LDS[row][s] = global[row][s^(row&7)]
    const int r8 = lane >> 3;
    const int cb = (lane & 7) ^ r8;
    const __bf16* gsrc[8];
    __bf16* ldst[8];
#pragma unroll
    for (int t = 0; t < 8; ++t) {
        int j = wave * 8 + t;
        if (j < 16) {
            int row = bm * 128 + j * 8 + r8;
            gsrc[t] = A + (size_t)row * K + cb * 8;
            ldst[t] = lsA + j * 512;
        } else {
            int jj = j - 16;
            int row = bn * 128 + jj * 8 + r8;
            gsrc[t] = Bw + (size_t)row * K + cb * 8;
            ldst[t] = lsB + jj * 512;
        }
    }

    // frag reads: row fr, global k-block g=kk*4+ks lives at LDS slot g^(fr&7)
    const int fr  = lane & 15;
    const int ks  = lane >> 4;
    const int sx  = fr & 7;
    const int sl0 = ((ks)     ^ sx) * 8;
    const int sl1 = ((4 + ks) ^ sx) * 8;
    const __bf16* arow[4];
    const __bf16* brow[4];
#pragma unroll
    for (int i = 0; i < 4; ++i) {
        arow[i] = lsA + (wm * 64 + i * 16 + fr) * 64;
        brow[i] = lsB + (wn * 64 + i * 16 + fr) * 64;
    }

    floatx4 acc[4][4];
    const floatx4 vzero = {0.f, 0.f, 0.f, 0.f};
#pragma unroll
    for (int mi = 0; mi < 4; ++mi)
#pragma unroll
        for (int ni = 0; ni < 4; ++ni) acc[mi][ni] = vzero;

    const int nk = K >> 6;
    int limit;
    if (LMODE == 0)      limit = (cnt_le(resp_s(bn * 128 + 127)) + 63) >> 6;
    else if (LMODE == 1) { int D = 4 * bn + 2; if (D > 126) D = 126;
                           limit = (cnt_le(D) + 63) >> 6; }
    else                 limit = (resp_s(bn * 128 + 127) + 64) >> 6;
    if (limit > nk) limit = nk;

    for (int it = 0; it < limit; ++it) {
        const int kt = it << 6;
        __syncthreads();
#pragma unroll
        for (int t = 0; t < 8; ++t)
            load_lds16((const void*)(gsrc[t] + kt), (void*)ldst[t]);
        __syncthreads();
        bf16x8 af[4], bf[4];
#pragma unroll
        for (int i = 0; i < 4; ++i) af[i] = *(const bf16x8*)(arow[i] + sl0);
#pragma unroll
        for (int i = 0; i < 4; ++i) bf[i] = *(const bf16x8*)(brow[i] + sl0);
#pragma unroll
        for (int mi = 0; mi < 4; ++mi)
#pragma unroll
            for (int ni = 0; ni < 4; ++ni)
                acc[mi][ni] = __builtin_amdgcn_mfma_f32_16x16x32_bf16(
                    af[mi], bf[ni], acc[mi][ni], 0, 0, 0);
#pragma unroll
        for (int i = 0; i < 4; ++i) af[i] = *(const bf16x8*)(arow[i] + sl1);
#pragma unroll
        for (int i = 0; i < 4; ++i) bf[i] = *(const bf16x8*)(brow[i] + sl1);
#pragma unroll
        for (int mi = 0; mi < 4; ++mi)
#pragma unroll
            for (int ni = 0; ni < 4; ++ni)
                acc[mi][ni] = __builtin_amdgcn_mfma_f32_16x16x32_bf16(
                    af[mi], bf[ni], acc[mi][ni], 0, 0, 0);
    }

    const int cn  = lane & 15;
    const int cr4 = (lane >> 4) * 4;
#pragma unroll
    for (int ni = 0; ni < 4; ++ni) {
        int col = bn * 128 + wn * 64 + ni * 16 + cn;
        float bv = bias[PERMBIAS ? invp_s(col) : col];
#pragma unroll
        for (int mi = 0; mi < 4; ++mi) {
            int row0 = bm * 128 + wm * 64 + mi * 16 + cr4;
#pragma unroll
            for (int q = 0; q < 4; ++q) {
                float v = acc[mi][ni][q] + bv;
                if (RELU) v = fmaxf(v, 0.f);
                if (TLAYOUT) {
                    // b = row0+q; b>>6 = bm*2+wm; b&63 = mi*16+cr4+q
                    size_t addr = (size_t)(bm * 2 + wm) * ((size_t)N * 64)
                                + (size_t)col * 64 + (mi * 16 + cr4 + q);
                    ((__bf16*)Cout)[addr] = (__bf16)v;
                } else if (OBF16) {
                    ((__bf16*)Cout)[(size_t)(row0 + q) * N + col] = (__bf16)v;
                } else {
                    ((float*)Cout)[(size_t)(row0 + q) * N + col] = v;
                }
            }
        }
    }
}

// ---------------------------------------------------------------------------
// Segment-parallel log-semiring chain, one thread per (batch, segment).
// theta (bf16) in batch-interleaved layout th2[b>>6][f][b&63].
// ---------------------------------------------------------------------------
__global__ __launch_bounds__(256)
void chain_seg(const __bf16* __restrict__ th2,  // [128][4096][64] bf16
               const float* __restrict__ x,     // [8192,128]
               float* __restrict__ P)           // [8192,18,16]
{
    const int b = blockIdx.x * 256 + threadIdx.x;
    const int s = blockIdx.y;                    // 0..17
    const int i0 = 1 + s * 7;
    const __bf16* tp = th2 + (size_t)(b >> 6) * (4096 * 64) + (b & 63)
                           + (size_t)i0 * 32 * 64;
    const float* xp = x + (size_t)b * 128 + i0;

    const float LOG2E = 1.4426950408889634f;
    const float C0    = 2.3052328943245633f;     // 0.5*log(2pi) + log(4)

    float M[4][4];
#pragma unroll
    for (int r = 0; r < 4; ++r)
#pragma unroll
        for (int c = 0; c < 4; ++c) M[r][c] = (r == c) ? 0.f : -1e30f;

    for (int ii = 0; ii < 7; ++ii) {
        float mu[16], al[16];
#pragma unroll
        for (int j = 0; j < 16; ++j) mu[j] = (float)tp[(size_t)j * 64];
#pragma unroll
        for (int j = 0; j < 16; ++j) al[j] = (float)tp[(size_t)(16 + j) * 64];
        float xv = xp[ii];
        tp += 32 * 64;
        float lp[16];
#pragma unroll
        for (int j = 0; j < 16; ++j) {
            float a = al[j];
            float e = fexp2(-a * LOG2E);
            float z = (xv - mu[j]) * e;
            lp[j] = (-0.5f * z * z - a - C0) * LOG2E;
        }
        float Mn[4][4];
#pragma unroll
        for (int r = 0; r < 4; ++r)
#pragma unroll
            for (int c = 0; c < 4; ++c) {
                float a0 = M[r][0] + lp[0 * 4 + c];
                float a1 = M[r][1] + lp[1 * 4 + c];
                float a2 = M[r][2] + lp[2 * 4 + c];
                float a3 = M[r][3] + lp[3 * 4 + c];
                float mx = fmaxf(fmaxf(a0, a1), fmaxf(a2, a3));
                float sm = fexp2(a0 - mx) + fexp2(a1 - mx) +
                           fexp2(a2 - mx) + fexp2(a3 - mx);
                Mn[r][c] = mx + flog2(sm);
            }
#pragma unroll
        for (int r = 0; r < 4; ++r)
#pragma unroll
            for (int c = 0; c < 4; ++c) M[r][c] = Mn[r][c];
    }

    float* pb = P + ((size_t)b * 18 + s) * 16;
#pragma unroll
    for (int r = 0; r < 4; ++r) {
        floatx4 o = {M[r][0], M[r][1], M[r][2], M[r][3]};
        *(floatx4*)(pb + r * 4) = o;
    }
}

// ---------------------------------------------------------------------------
// Combine: fold 18 segment matrices + first/last boundary vectors per batch.
// ---------------------------------------------------------------------------
__global__ __launch_bounds__(256)
void chain_fin(const __bf16* __restrict__ th2,  // [128][4096][64] bf16
               const float* __restrict__ x,     // [8192,128]
               const float* __restrict__ P,     // [8192,18,16]
               float* __restrict__ out)         // [8192]
{
    const int tid  = threadIdx.x;
    const int lane = tid & 63;
    const int r    = lane & 3;
    const int l0   = lane & 60;
    const int b    = blockIdx.x * 64 + (tid >> 2);
    const __bf16* tb = th2 + (size_t)(b >> 6) * (4096 * 64) + (b & 63);

    const float LOG2E = 1.4426950408889634f;
    const float LN2   = 0.6931471805599453f;
    const float C0    = 2.3052328943245633f;

    const float* Pb = P + (size_t)b * 288;       // 18*16
    floatx4 m0 = *(const floatx4*)(Pb + r * 4);
    float M[4] = {m0[0], m0[1], m0[2], m0[3]};

#pragma unroll
    for (int s = 1; s < 18; ++s) {
        floatx4 lr = *(const floatx4*)(Pb + s * 16 + r * 4);
        float Mn[4];
#pragma unroll
        for (int c = 0; c < 4; ++c) {
            float a0 = M[0] + __shfl(lr[c], l0 + 0);
            float a1 = M[1] + __shfl(lr[c], l0 + 1);
            float a2 = M[2] + __shfl(lr[c], l0 + 2);
            float a3 = M[3] + __shfl(lr[c], l0 + 3);
            float mx = fmaxf(fmaxf(a0, a1), fmaxf(a2, a3));
            float sm = fexp2(a0 - mx) + fexp2(a1 - mx) + fexp2(a2 - mx) + fexp2(a3 - mx);
            Mn[c] = mx + flog2(sm);
        }
#pragma unroll
        for (int k = 0; k < 4; ++k) M[k] = Mn[k];
    }

    float xl = x[(size_t)b * 128 + 127];
    float a[4];
#pragma unroll
    for (int c = 0; c < 4; ++c) {
        float mu_ = (float)tb[(size_t)(4064 + c * 4) * 64];
        float al_ = (float)tb[(size_t)(4064 + 16 + c * 4) * 64];
        float e = fexp2(-al_ * LOG2E);
        float z = (xl - mu_) * e;
        float lp2 = (-0.5f * z * z - al_ - C0) * LOG2E;
        a[c] = M[c] + lp2;
    }
    float mx = fmaxf(fmaxf(a[0], a[1]), fmaxf(a[2], a[3]));
    float tr = mx + flog2(fexp2(a[0] - mx) + fexp2(a[1] - mx) +
                          fexp2(a[2] - mx) + fexp2(a[3] - mx));

    float x0  = x[(size_t)b * 128];
    float muf = (float)tb[(size_t)r * 64];
    float alf = (float)tb[(size_t)(16 + r) * 64];
    float ef = fexp2(-alf * LOG2E);
    float zf = (x0 - muf) * ef;
    float f2 = (-0.5f * zf * zf - alf - C0) * LOG2E;
    float v = f2 + tr;
    float m1 = fmaxf(v, __shfl_xor(v, 1));
    float m2 = fmaxf(m1, __shfl_xor(m1, 2));
    float sum = fexp2(v - m2);
    sum += __shfl_xor(sum, 1);
    sum += __shfl_xor(sum, 2);
    if (r == 0) out[b] = (m2 + flog2(sum)) * LN2;
}

// ---------------------------------------------------------------------------
extern "C" void kernel_launch(void* const* d_in, const int* in_sizes, int n_in,
                              void* d_out, int out_size, void* d_ws, size_t ws_size,
                              hipStream_t stream)
{
    (void)in_sizes; (void)n_in; (void)out_size; (void)ws_size;
    const float* x  = (const float*)d_in[0];
    const float* W0 = (const float*)d_in[1];
    const float* b0 = (const float*)d_in[2];
    const float* W1 = (const float*)d_in[3];
    const float* b1 = (const float*)d_in[4];
    const float* W2 = (const float*)d_in[5];
    const float* b2 = (const float*)d_in[6];
    const float* W3 = (const float*)d_in[7];
    const float* b3 = (const float*)d_in[8];

    char* ws = (char*)d_ws;
    size_t off = 0;
    auto alloc = [&](size_t bytes) { char* p = ws + off; off += bytes; return p; };
    __bf16* xb  = (__bf16*)alloc((size_t)8192 * 128 * 2);    // 2 MB
    __bf16* w0m = (__bf16*)alloc((size_t)2048 * 128 * 2);    // 0.5 MB
    __bf16* w1m = (__bf16*)alloc((size_t)2048 * 2048 * 2);   // 8 MB
    __bf16* w2m = (__bf16*)alloc((size_t)2048 * 2048 * 2);   // 8 MB
    __bf16* w3m = (__bf16*)alloc((size_t)4096 * 2048 * 2);   // 16 MB
    __bf16* h1  = (__bf16*)alloc((size_t)8192 * 2048 * 2);   // 32 MB
    __bf16* h2  = (__bf16*)alloc((size_t)8192 * 2048 * 2);   // 32 MB
    __bf16* th  = (__bf16*)alloc((size_t)8192 * 4096 * 2);   // 64 MB (batch-interleaved)
    __bf16* h3  = h1;            // h1 dead after GEMM2; reuse for h3
    float*  P   = (float*)h2;    // h2 dead after GEMM3; P = 9.4 MB << 32 MB

    // fused masked + exact-degree-sorted weight prep
    prep_all<<<8832, 256, 0, stream>>>(x, W0, W1, W2, W3, xb, w0m, w1m, w2m, w3m);

    // GEMM0: sorted N, natural K=128 (LMODE 2)
    gemm_bt<true, true, false, true, 2><<<dim3(64, 16), 256, 0, stream>>>(
        xb, w0m, b0, h1, 2048, 128);
    // GEMM1/2: sorted N, sorted K (LMODE 0)
    gemm_bt<true, true, false, true, 0><<<dim3(64, 16), 256, 0, stream>>>(
        h1, w1m, b1, h2, 2048, 2048);
    gemm_bt<true, true, false, true, 0><<<dim3(64, 16), 256, 0, stream>>>(
        h2, w2m, b2, h3, 2048, 2048);
    // GEMM3: natural N, sorted K (LMODE 1), theta bf16 TLAYOUT store
    gemm_bt<false, false, true, false, 1><<<dim3(64, 32), 256, 0, stream>>>(
        h3, w3m, b3, th, 4096, 2048);

    // segment-parallel log-semiring chain
    chain_seg<<<dim3(32, 18), 256, 0, stream>>>(th, x, P);
    chain_fin<<<128, 256, 0, stream>>>(th, x, P, (float*)d_out);
}